// Round 8
// baseline (269.810 us; speedup 1.0000x reference)
//
#include <hip/hip_runtime.h>
#include <stdint.h>

#define NUM_HEADS 12
#define HEAD_DIM 64
#define EMB 768
#define SEQ 4096
#define BATCH 2
#define ROWS (BATCH*SEQ)     // 8192
#define DQKV (3*EMB)         // 2304

typedef __attribute__((ext_vector_type(8))) __bf16 bf16x8;
typedef __attribute__((ext_vector_type(4))) float floatx4;

static __device__ __forceinline__ unsigned short f2bf(float f) {
  unsigned int u = __float_as_uint(f);
  u += 0x7FFFu + ((u >> 16) & 1u);          // round-to-nearest-even
  return (unsigned short)(u >> 16);
}

static __device__ __forceinline__ float bf2f(unsigned short h) {
  return __uint_as_float(((unsigned int)h) << 16);
}

// truncating pack: two fp32 -> bf16x2 dword {hi(b),hi(a)} — 1 v_perm, no adds
static __device__ __forceinline__ unsigned int pack_bf2_trunc(float a, float b) {
  return __builtin_amdgcn_perm(__float_as_uint(b), __float_as_uint(a), 0x07060302u);
}

static __device__ __forceinline__ void async_cp16(void* lds, const void* g) {
  __builtin_amdgcn_global_load_lds(
      (__attribute__((address_space(1))) void*)(g),
      (__attribute__((address_space(3))) void*)(lds), 16, 0, 0);
}

// key permutation within a 32-key group: PV lane (quad fq) reads its 8 keys
// {4fq+0..3, 16+4fq+0..3} as ONE contiguous 16B chunk (conflict-free b128).
static __device__ __forceinline__ int perm_key(int nn) {
  return (nn & ~31) | (((nn >> 2) & 3) * 8 + ((nn >> 4) & 1) * 4 + (nn & 3));
}

// ---------------- fp32 -> bf16 convert (x and w fused) ----------------
#define N4X (ROWS*EMB/4)
#define N4W (DQKV*EMB/4)
__global__ __launch_bounds__(256) void cvt2_kernel(
    const float* __restrict__ x, const float* __restrict__ w,
    unsigned short* __restrict__ xb, unsigned short* __restrict__ wb) {
  int i = blockIdx.x * blockDim.x + threadIdx.x;
  const float4* src;
  ushort4* dst;
  if (i < N4X) { src = (const float4*)x; dst = (ushort4*)xb; }
  else { i -= N4X; if (i >= N4W) return; src = (const float4*)w; dst = (ushort4*)wb; }
  float4 v = src[i];
  ushort4 o;
  o.x = f2bf(v.x); o.y = f2bf(v.y); o.z = f2bf(v.z); o.w = f2bf(v.w);
  dst[i] = o;
}

// ---------------- unified QKV projection GEMM (unchanged from R7) --------
__global__ __launch_bounds__(256) void qkv_gemm_kernel(
    const unsigned short* __restrict__ xb, const unsigned short* __restrict__ wb,
    const float* __restrict__ bias,
    unsigned short* __restrict__ Qb, unsigned short* __restrict__ Kb,
    unsigned short* __restrict__ Vt) {
  __shared__ unsigned short As[128 * 64];
  __shared__ unsigned short Bs[128 * 64];
  const int t = threadIdx.x;
  const int lane = t & 63;
  const int w = t >> 6;
  const int wm = w >> 1, wn = w & 1;
  const int fr = lane & 15, fq = lane >> 4;
  const int fx = fr & 7;
  const int m0 = blockIdx.x * 128;
  const int n0 = blockIdx.y * 128;
  const int sel = n0 / EMB;       // 0=Q 1=K 2=V (block-uniform)
  const int lr = t >> 3;          // 0..31
  const int sc = t & 7;           // chunk col 0..7

  floatx4 acc[4][4];
#pragma unroll
  for (int i = 0; i < 4; ++i)
#pragma unroll
    for (int j = 0; j < 4; ++j) acc[i][j] = (floatx4)(0.0f);

  if (sel < 2) {
    for (int k0 = 0; k0 < EMB; k0 += 64) {
      __syncthreads();
#pragma unroll
      for (int i = 0; i < 4; ++i) {
        const int rr = i*32 + lr;
        const int cg = ((sc ^ (lr & 7)) * 8);
        async_cp16(&As[rr*64 + sc*8], &xb[(size_t)(m0 + rr)*EMB + k0 + cg]);
        async_cp16(&Bs[rr*64 + sc*8], &wb[(size_t)(n0 + rr)*EMB + k0 + cg]);
      }
      __syncthreads();
#pragma unroll
      for (int ks = 0; ks < 2; ++ks) {
        bf16x8 af[4], bfr[4];
#pragma unroll
        for (int i = 0; i < 4; ++i)
          af[i] = *(const bf16x8*)&As[(wm*64 + i*16 + fr)*64 + (((ks*4+fq) ^ fx)*8)];
#pragma unroll
        for (int j = 0; j < 4; ++j)
          bfr[j] = *(const bf16x8*)&Bs[(wn*64 + j*16 + fr)*64 + (((ks*4+fq) ^ fx)*8)];
#pragma unroll
        for (int i = 0; i < 4; ++i)
#pragma unroll
          for (int j = 0; j < 4; ++j)
            acc[i][j] = __builtin_amdgcn_mfma_f32_16x16x32_bf16(bfr[j], af[i], acc[i][j], 0, 0, 0);
      }
    }
    // D layout: row (feature) = j*16 + fq*4 + reg, col (x row) = i*16 + fr.
    const float qscale = 0.125f * 1.4426950408889634f;  // 1/sqrt(64)*log2(e)
    const float sc2 = (sel == 0) ? qscale : 1.0f;
    unsigned short* dst = (sel == 0) ? Qb : Kb;
#pragma unroll
    for (int i = 0; i < 4; ++i) {
      const int mr = m0 + wm*64 + i*16 + fr;      // x row
      const int b = mr / SEQ;
      const int nn = mr - b*SEQ;
#pragma unroll
      for (int j = 0; j < 4; ++j) {
        const int og = n0 + wn*64 + j*16 + fq*4;  // feature base (4 consecutive)
        const int oo = og - sel*EMB;
        const int hh = oo >> 6, dd = oo & 63;
        const float4 bv = *(const float4*)&bias[og];
        ushort4 pk;
        pk.x = f2bf((acc[i][j][0] + bv.x) * sc2);
        pk.y = f2bf((acc[i][j][1] + bv.y) * sc2);
        pk.z = f2bf((acc[i][j][2] + bv.z) * sc2);
        pk.w = f2bf((acc[i][j][3] + bv.w) * sc2);
        *(ushort4*)&dst[(((size_t)(b*NUM_HEADS + hh))*SEQ + nn)*HEAD_DIM + dd] = pk;
      }
    }
  } else {
    for (int k0 = 0; k0 < EMB; k0 += 64) {
      __syncthreads();
#pragma unroll
      for (int i = 0; i < 4; ++i) {
        const int rr = i*32 + lr;
        const int cg = ((sc ^ (lr & 7)) * 8);
        async_cp16(&As[rr*64 + sc*8], &xb[(size_t)(m0 + rr)*EMB + k0 + cg]);
        async_cp16(&Bs[rr*64 + sc*8], &wb[(size_t)(n0 + rr)*EMB + k0 + cg]);
      }
      __syncthreads();
#pragma unroll
      for (int ks = 0; ks < 2; ++ks) {
        bf16x8 af[4], bfr[4];
#pragma unroll
        for (int i = 0; i < 4; ++i)
          af[i] = *(const bf16x8*)&As[(wm*64 + i*16 + fr)*64 + (((ks*4+fq) ^ fx)*8)];
#pragma unroll
        for (int j = 0; j < 4; ++j)
          bfr[j] = *(const bf16x8*)&Bs[(wn*64 + j*16 + fr)*64 + (((ks*4+fq) ^ fx)*8)];
#pragma unroll
        for (int i = 0; i < 4; ++i)
#pragma unroll
          for (int j = 0; j < 4; ++j)
            acc[i][j] = __builtin_amdgcn_mfma_f32_16x16x32_bf16(af[i], bfr[j], acc[i][j], 0, 0, 0);
      }
    }
    // D layout: row (x row) = i*16 + fq*4 + reg, col (feature) = j*16 + fr.
#pragma unroll
    for (int i = 0; i < 4; ++i) {
      const int mr = m0 + wm*64 + i*16 + fq*4;    // x row base (4 consecutive)
      const int b = mr / SEQ;
      const int nn = perm_key(mr - b*SEQ);        // key-permuted position
#pragma unroll
      for (int j = 0; j < 4; ++j) {
        const int feat = n0 + wn*64 + j*16 + fr;
        const int oo = feat - 2*EMB;
        const int hh = oo >> 6, dd = oo & 63;
        const float bv = bias[feat];
        ushort4 pk;
        pk.x = f2bf(acc[i][j][0] + bv);
        pk.y = f2bf(acc[i][j][1] + bv);
        pk.z = f2bf(acc[i][j][2] + bv);
        pk.w = f2bf(acc[i][j][3] + bv);
        *(ushort4*)&Vt[(((size_t)(b*NUM_HEADS + hh))*HEAD_DIM + dd)*SEQ + nn] = pk;
      }
    }
  }
}

// ---------------- flash attention, S^T formulation ----------------
// grid (SEQ/64, BATCH*NUM_HEADS) = 1536 blocks -> 8 blocks/CU (16 waves/CU).
// Block = 2 waves x 32 q-rows (g=2 kept: each K/V fragment read feeds 2 MFMAs
// — the R4 lesson). 64-key tiles -> 16 KB LDS/block so 8 blocks fit; barrier
// drains of one block hide under the other 7. launch_bounds(128,4): VGPR cap
// 128 (kernel needs ~64; the (256,5)=cap-102 variant spilled — R5).
__global__ __launch_bounds__(128, 4) void attn_kernel(
    const unsigned short* __restrict__ Qb, const unsigned short* __restrict__ Kb,
    const unsigned short* __restrict__ Vt, unsigned short* __restrict__ Oo) {
  __shared__ unsigned short Ks[64 * 64];    // [key][d], 8 chunks/row, swizzled
  __shared__ unsigned short Vs[64 * 64];    // [d][perm key], 8 chunks/row, swizzled
  const int t = threadIdx.x;
  const int lane = t & 63;
  const int w = t >> 6;                     // 0..1
  const int fr = lane & 15, fq = lane >> 4;
  const int fx = fr & 7;
  const int bh = blockIdx.y;
  const int q0 = blockIdx.x * 64 + w * 32;

  // Q fragments (B-operand of S^T): per q-group g, rows q0+g*16+fr.
  bf16x8 aq[2][2];
#pragma unroll
  for (int g = 0; g < 2; ++g) {
    const size_t qoff = ((size_t)bh * SEQ + q0 + g*16 + fr) * HEAD_DIM;
    aq[g][0] = *(const bf16x8*)&Qb[qoff + fq*8];
    aq[g][1] = *(const bf16x8*)&Qb[qoff + 32 + fq*8];
  }

  union { unsigned int u[4]; bf16x8 b; } onesu;
  onesu.u[0] = onesu.u[1] = onesu.u[2] = onesu.u[3] = 0x3F803F80u;
  const bf16x8 onesb = onesu.b;

  floatx4 o[2][4];
  floatx4 lsum[2];
#pragma unroll
  for (int g = 0; g < 2; ++g) {
    lsum[g] = (floatx4)(0.f);
#pragma unroll
    for (int d = 0; d < 4; ++d) o[g][d] = (floatx4)(0.f);
  }

  const size_t kb = (size_t)bh * SEQ * HEAD_DIM;
  const size_t vb = (size_t)bh * HEAD_DIM * SEQ;

  for (int kc = 0; kc < SEQ; kc += 64) {
    __syncthreads();
#pragma unroll
    for (int i = 0; i < 4; ++i) {           // Ks: 512 chunks, rows of 8
      const int chunk = i*128 + t;
      const int r = chunk >> 3, c = chunk & 7;
      async_cp16(&Ks[chunk*8], &Kb[kb + (size_t)(kc + r)*HEAD_DIM + ((c ^ (r&7))*8)]);
    }
#pragma unroll
    for (int i = 0; i < 4; ++i) {           // Vs: 512 chunks, rows of 8
      const int chunk = i*128 + t;
      const int r = chunk >> 3, c = chunk & 7;
      async_cp16(&Vs[chunk*8], &Vt[vb + (size_t)r*SEQ + kc + ((c ^ (r&7))*8)]);
    }
    __syncthreads();

#pragma unroll
    for (int J = 0; J < 2; ++J) {           // 32-key chunks
      floatx4 z[2][2];
#pragma unroll
      for (int jj = 0; jj < 2; ++jj) {
        const int row = (J*2 + jj)*16 + fr; // key row in Ks (0..63)
        bf16x8 k0 = *(const bf16x8*)&Ks[row*64 + ((fq ^ fx)*8)];
        bf16x8 k1 = *(const bf16x8*)&Ks[row*64 + (((fq+4) ^ fx)*8)];
#pragma unroll
        for (int g = 0; g < 2; ++g) {
          floatx4 accz = (floatx4)(0.f);
          accz = __builtin_amdgcn_mfma_f32_16x16x32_bf16(k0, aq[g][0], accz, 0, 0, 0);
          accz = __builtin_amdgcn_mfma_f32_16x16x32_bf16(k1, aq[g][1], accz, 0, 0, 0);
          z[g][jj] = accz;                  // S^T: key=16(2J+jj)+fq*4+r, q=fr
        }
      }
      // exp2 + truncate-pack to PV A-fragment (register-only transpose)
      bf16x8 ap[2];
#pragma unroll
      for (int g = 0; g < 2; ++g) {
        float e0 = __builtin_amdgcn_exp2f(z[g][0][0]);
        float e1 = __builtin_amdgcn_exp2f(z[g][0][1]);
        float e2 = __builtin_amdgcn_exp2f(z[g][0][2]);
        float e3 = __builtin_amdgcn_exp2f(z[g][0][3]);
        float e4 = __builtin_amdgcn_exp2f(z[g][1][0]);
        float e5 = __builtin_amdgcn_exp2f(z[g][1][1]);
        float e6 = __builtin_amdgcn_exp2f(z[g][1][2]);
        float e7 = __builtin_amdgcn_exp2f(z[g][1][3]);
        union { unsigned int u[4]; bf16x8 b; } cv;
        cv.u[0] = pack_bf2_trunc(e0, e1);
        cv.u[1] = pack_bf2_trunc(e2, e3);
        cv.u[2] = pack_bf2_trunc(e4, e5);
        cv.u[3] = pack_bf2_trunc(e6, e7);
        ap[g] = cv.b;
      }
      // l += P * ones  (row-sum on the MFMA pipe; D rows = q like O)
#pragma unroll
      for (int g = 0; g < 2; ++g)
        lsum[g] = __builtin_amdgcn_mfma_f32_16x16x32_bf16(ap[g], onesb, lsum[g], 0, 0, 0);
      // PV: O[q][d] += P[q][key] V[key][d] over keys [32J, 32J+32)
#pragma unroll
      for (int dt = 0; dt < 4; ++dt) {
        const int r = dt*16 + fr;           // d row in Vs
        const bf16x8 vvb = *(const bf16x8*)&Vs[r*64 + (((4*J + fq) ^ fx)*8)];
#pragma unroll
        for (int g = 0; g < 2; ++g)
          o[g][dt] = __builtin_amdgcn_mfma_f32_16x16x32_bf16(ap[g], vvb, o[g][dt], 0, 0, 0);
      }
    }
  }

  const int b = bh / NUM_HEADS, hh = bh - b*NUM_HEADS;
#pragma unroll
  for (int g = 0; g < 2; ++g)
#pragma unroll
    for (int r4 = 0; r4 < 4; ++r4) {
      const float li = 1.0f / lsum[g][r4];  // l[q=fq*4+r4] — same layout as O
      const size_t obase = ((size_t)b*SEQ + q0 + g*16 + fq*4 + r4)*EMB + hh*HEAD_DIM;
#pragma unroll
      for (int dt = 0; dt < 4; ++dt)
        Oo[obase + dt*16 + fr] = f2bf(o[g][dt][r4] * li);
    }
}

// ---------------- residual + LayerNorm: one wave per row ----------------
__global__ __launch_bounds__(256) void ln_kernel(
    const float* __restrict__ x, const unsigned short* __restrict__ att,
    const float* __restrict__ gamma, const float* __restrict__ beta,
    float* __restrict__ out) {
  const int row = blockIdx.x * 4 + (threadIdx.x >> 6);
  const int lane = threadIdx.x & 63;
  const size_t base = (size_t)row * EMB;
  float4 v[3];
  float s = 0.f, s2 = 0.f;
#pragma unroll
  for (int k = 0; k < 3; ++k) {
    const int c = lane*4 + k*256;
    const float4 xv = *(const float4*)&x[base + c];
    const ushort4 a4 = *(const ushort4*)&att[base + c];
    v[k].x = xv.x + bf2f(a4.x);
    v[k].y = xv.y + bf2f(a4.y);
    v[k].z = xv.z + bf2f(a4.z);
    v[k].w = xv.w + bf2f(a4.w);
    s  += (v[k].x + v[k].y) + (v[k].z + v[k].w);
    s2 += (v[k].x*v[k].x + v[k].y*v[k].y) + (v[k].z*v[k].z + v[k].w*v[k].w);
  }
#pragma unroll
  for (int off = 1; off < 64; off <<= 1) {
    s  += __shfl_xor(s,  off);
    s2 += __shfl_xor(s2, off);
  }
  const float mean = s * (1.0f / EMB);
  const float var  = s2 * (1.0f / EMB) - mean * mean;
  const float rstd = rsqrtf(var + 1e-5f);
#pragma unroll
  for (int k = 0; k < 3; ++k) {
    const int c = lane*4 + k*256;
    const float4 g4 = *(const float4*)&gamma[c];
    const float4 b4 = *(const float4*)&beta[c];
    float4 ov;
    ov.x = (v[k].x - mean) * rstd * g4.x + b4.x;
    ov.y = (v[k].y - mean) * rstd * g4.y + b4.y;
    ov.z = (v[k].z - mean) * rstd * g4.z + b4.z;
    ov.w = (v[k].w - mean) * rstd * g4.w + b4.w;
    *(float4*)&out[base + c] = ov;
  }
}

extern "C" void kernel_launch(void* const* d_in, const int* in_sizes, int n_in,
                              void* d_out, int out_size, void* d_ws, size_t ws_size,
                              hipStream_t stream) {
  const float* x      = (const float*)d_in[0];
  const float* w_qkv  = (const float*)d_in[1];
  const float* b_qkv  = (const float*)d_in[2];
  const float* gamma  = (const float*)d_in[3];
  const float* beta   = (const float*)d_in[4];
  float* out = (float*)d_out;

  unsigned short* xb = (unsigned short*)d_ws;                 // 8192*768 bf16
  unsigned short* wb = xb + (size_t)ROWS * EMB;               // 2304*768 bf16
  unsigned short* Qb = wb + (size_t)DQKV * EMB;               // [b,h,n,64] bf16 (scaled)
  unsigned short* Kb = Qb + (size_t)ROWS * EMB;               // [b,h,n,64] bf16
  unsigned short* Vt = Kb + (size_t)ROWS * EMB;               // [b,h,64,perm n] bf16
  unsigned short* att = Vt + (size_t)ROWS * EMB;              // [b,n,768] bf16

  cvt2_kernel<<<(N4X + N4W + 255)/256, 256, 0, stream>>>(x, w_qkv, xb, wb);
  qkv_gemm_kernel<<<dim3(ROWS/128, DQKV/128), 256, 0, stream>>>(xb, wb, b_qkv, Qb, Kb, Vt);
  attn_kernel<<<dim3(SEQ/64, BATCH*NUM_HEADS), 128, 0, stream>>>(Qb, Kb, Vt, att);
  ln_kernel<<<ROWS/4, 256, 0, stream>>>(x, att, gamma, beta, out);
}

// Round 9
// 245.869 us; speedup vs baseline: 1.0974x; 1.0974x over previous
//
#include <hip/hip_runtime.h>
#include <stdint.h>

#define NUM_HEADS 12
#define HEAD_DIM 64
#define EMB 768
#define SEQ 4096
#define BATCH 2
#define ROWS (BATCH*SEQ)     // 8192
#define DQKV (3*EMB)         // 2304

typedef __attribute__((ext_vector_type(8))) __bf16 bf16x8;
typedef __attribute__((ext_vector_type(4))) float floatx4;

static __device__ __forceinline__ unsigned short f2bf(float f) {
  unsigned int u = __float_as_uint(f);
  u += 0x7FFFu + ((u >> 16) & 1u);          // round-to-nearest-even
  return (unsigned short)(u >> 16);
}

static __device__ __forceinline__ float bf2f(unsigned short h) {
  return __uint_as_float(((unsigned int)h) << 16);
}

// truncating pack: two fp32 -> bf16x2 dword {hi(b),hi(a)} — 1 v_perm, no adds
static __device__ __forceinline__ unsigned int pack_bf2_trunc(float a, float b) {
  return __builtin_amdgcn_perm(__float_as_uint(b), __float_as_uint(a), 0x07060302u);
}

static __device__ __forceinline__ void async_cp16(void* lds, const void* g) {
  __builtin_amdgcn_global_load_lds(
      (__attribute__((address_space(1))) void*)(g),
      (__attribute__((address_space(3))) void*)(lds), 16, 0, 0);
}

// key permutation within a 32-key group: PV lane (quad fq) reads its 8 keys
// {4fq+0..3, 16+4fq+0..3} as ONE contiguous 16B chunk (conflict-free b128).
static __device__ __forceinline__ int perm_key(int nn) {
  return (nn & ~31) | (((nn >> 2) & 3) * 8 + ((nn >> 4) & 1) * 4 + (nn & 3));
}

// ---------------- fp32 -> bf16 convert (x and w fused) ----------------
#define N4X (ROWS*EMB/4)
#define N4W (DQKV*EMB/4)
__global__ __launch_bounds__(256) void cvt2_kernel(
    const float* __restrict__ x, const float* __restrict__ w,
    unsigned short* __restrict__ xb, unsigned short* __restrict__ wb) {
  int i = blockIdx.x * blockDim.x + threadIdx.x;
  const float4* src;
  ushort4* dst;
  if (i < N4X) { src = (const float4*)x; dst = (ushort4*)xb; }
  else { i -= N4X; if (i >= N4W) return; src = (const float4*)w; dst = (ushort4*)wb; }
  float4 v = src[i];
  ushort4 o;
  o.x = f2bf(v.x); o.y = f2bf(v.y); o.z = f2bf(v.z); o.w = f2bf(v.w);
  dst[i] = o;
}

// ---------------- unified QKV projection GEMM (unchanged from R7) --------
__global__ __launch_bounds__(256) void qkv_gemm_kernel(
    const unsigned short* __restrict__ xb, const unsigned short* __restrict__ wb,
    const float* __restrict__ bias,
    unsigned short* __restrict__ Qb, unsigned short* __restrict__ Kb,
    unsigned short* __restrict__ Vt) {
  __shared__ unsigned short As[128 * 64];
  __shared__ unsigned short Bs[128 * 64];
  const int t = threadIdx.x;
  const int lane = t & 63;
  const int w = t >> 6;
  const int wm = w >> 1, wn = w & 1;
  const int fr = lane & 15, fq = lane >> 4;
  const int fx = fr & 7;
  const int m0 = blockIdx.x * 128;
  const int n0 = blockIdx.y * 128;
  const int sel = n0 / EMB;       // 0=Q 1=K 2=V (block-uniform)
  const int lr = t >> 3;          // 0..31
  const int sc = t & 7;           // chunk col 0..7

  floatx4 acc[4][4];
#pragma unroll
  for (int i = 0; i < 4; ++i)
#pragma unroll
    for (int j = 0; j < 4; ++j) acc[i][j] = (floatx4)(0.0f);

  if (sel < 2) {
    for (int k0 = 0; k0 < EMB; k0 += 64) {
      __syncthreads();
#pragma unroll
      for (int i = 0; i < 4; ++i) {
        const int rr = i*32 + lr;
        const int cg = ((sc ^ (lr & 7)) * 8);
        async_cp16(&As[rr*64 + sc*8], &xb[(size_t)(m0 + rr)*EMB + k0 + cg]);
        async_cp16(&Bs[rr*64 + sc*8], &wb[(size_t)(n0 + rr)*EMB + k0 + cg]);
      }
      __syncthreads();
#pragma unroll
      for (int ks = 0; ks < 2; ++ks) {
        bf16x8 af[4], bfr[4];
#pragma unroll
        for (int i = 0; i < 4; ++i)
          af[i] = *(const bf16x8*)&As[(wm*64 + i*16 + fr)*64 + (((ks*4+fq) ^ fx)*8)];
#pragma unroll
        for (int j = 0; j < 4; ++j)
          bfr[j] = *(const bf16x8*)&Bs[(wn*64 + j*16 + fr)*64 + (((ks*4+fq) ^ fx)*8)];
#pragma unroll
        for (int i = 0; i < 4; ++i)
#pragma unroll
          for (int j = 0; j < 4; ++j)
            acc[i][j] = __builtin_amdgcn_mfma_f32_16x16x32_bf16(bfr[j], af[i], acc[i][j], 0, 0, 0);
      }
    }
    // D layout: row (feature) = j*16 + fq*4 + reg, col (x row) = i*16 + fr.
    const float qscale = 0.125f * 1.4426950408889634f;  // 1/sqrt(64)*log2(e)
    const float sc2 = (sel == 0) ? qscale : 1.0f;
    unsigned short* dst = (sel == 0) ? Qb : Kb;
#pragma unroll
    for (int i = 0; i < 4; ++i) {
      const int mr = m0 + wm*64 + i*16 + fr;      // x row
      const int b = mr / SEQ;
      const int nn = mr - b*SEQ;
#pragma unroll
      for (int j = 0; j < 4; ++j) {
        const int og = n0 + wn*64 + j*16 + fq*4;  // feature base (4 consecutive)
        const int oo = og - sel*EMB;
        const int hh = oo >> 6, dd = oo & 63;
        const float4 bv = *(const float4*)&bias[og];
        ushort4 pk;
        pk.x = f2bf((acc[i][j][0] + bv.x) * sc2);
        pk.y = f2bf((acc[i][j][1] + bv.y) * sc2);
        pk.z = f2bf((acc[i][j][2] + bv.z) * sc2);
        pk.w = f2bf((acc[i][j][3] + bv.w) * sc2);
        *(ushort4*)&dst[(((size_t)(b*NUM_HEADS + hh))*SEQ + nn)*HEAD_DIM + dd] = pk;
      }
    }
  } else {
    for (int k0 = 0; k0 < EMB; k0 += 64) {
      __syncthreads();
#pragma unroll
      for (int i = 0; i < 4; ++i) {
        const int rr = i*32 + lr;
        const int cg = ((sc ^ (lr & 7)) * 8);
        async_cp16(&As[rr*64 + sc*8], &xb[(size_t)(m0 + rr)*EMB + k0 + cg]);
        async_cp16(&Bs[rr*64 + sc*8], &wb[(size_t)(n0 + rr)*EMB + k0 + cg]);
      }
      __syncthreads();
#pragma unroll
      for (int ks = 0; ks < 2; ++ks) {
        bf16x8 af[4], bfr[4];
#pragma unroll
        for (int i = 0; i < 4; ++i)
          af[i] = *(const bf16x8*)&As[(wm*64 + i*16 + fr)*64 + (((ks*4+fq) ^ fx)*8)];
#pragma unroll
        for (int j = 0; j < 4; ++j)
          bfr[j] = *(const bf16x8*)&Bs[(wn*64 + j*16 + fr)*64 + (((ks*4+fq) ^ fx)*8)];
#pragma unroll
        for (int i = 0; i < 4; ++i)
#pragma unroll
          for (int j = 0; j < 4; ++j)
            acc[i][j] = __builtin_amdgcn_mfma_f32_16x16x32_bf16(af[i], bfr[j], acc[i][j], 0, 0, 0);
      }
    }
    // D layout: row (x row) = i*16 + fq*4 + reg, col (feature) = j*16 + fr.
#pragma unroll
    for (int i = 0; i < 4; ++i) {
      const int mr = m0 + wm*64 + i*16 + fq*4;    // x row base (4 consecutive)
      const int b = mr / SEQ;
      const int nn = perm_key(mr - b*SEQ);        // key-permuted position
#pragma unroll
      for (int j = 0; j < 4; ++j) {
        const int feat = n0 + wn*64 + j*16 + fr;
        const int oo = feat - 2*EMB;
        const int hh = oo >> 6, dd = oo & 63;
        const float bv = bias[feat];
        ushort4 pk;
        pk.x = f2bf(acc[i][j][0] + bv);
        pk.y = f2bf(acc[i][j][1] + bv);
        pk.z = f2bf(acc[i][j][2] + bv);
        pk.w = f2bf(acc[i][j][3] + bv);
        *(ushort4*)&Vt[(((size_t)(b*NUM_HEADS + hh))*HEAD_DIM + dd)*SEQ + nn] = pk;
      }
    }
  }
}

// ---------------- flash attention, S^T + pipelined softmax ----------------
// grid (SEQ/128, BATCH*NUM_HEADS), 256 threads = 4 waves x 32 q-rows (g=2).
// Vs split into two 64x64 halves: replicates R8's measured 0-conflict bank
// pattern while keeping 128-key tiles (R6 one-piece 128-wide Vs caused the
// residual 6.29e6 conflict-cycles). J-loop software-pipelined: z[J+1]'s
// S-MFMAs issue before exp2/pack of z[J], so the matrix pipe executes in the
// background of the softmax VALU burst instead of alternating with it.
__global__ __launch_bounds__(256, 4) void attn_kernel(
    const unsigned short* __restrict__ Qb, const unsigned short* __restrict__ Kb,
    const unsigned short* __restrict__ Vt, unsigned short* __restrict__ Oo) {
  __shared__ unsigned short Ks[128 * 64];     // [key][d], 8 chunks/row, swizzled
  __shared__ unsigned short Vs[2][64 * 64];   // [half][d][perm key], 8 chunks/row
  const int t = threadIdx.x;
  const int lane = t & 63;
  const int w = t >> 6;                     // 0..3
  const int fr = lane & 15, fq = lane >> 4;
  const int fx = fr & 7;
  const int bh = blockIdx.y;
  const int q0 = blockIdx.x * 128 + w * 32;

  // Q fragments (B-operand of S^T): per q-group g, rows q0+g*16+fr.
  bf16x8 aq[2][2];
#pragma unroll
  for (int g = 0; g < 2; ++g) {
    const size_t qoff = ((size_t)bh * SEQ + q0 + g*16 + fr) * HEAD_DIM;
    aq[g][0] = *(const bf16x8*)&Qb[qoff + fq*8];
    aq[g][1] = *(const bf16x8*)&Qb[qoff + 32 + fq*8];
  }

  union { unsigned int u[4]; bf16x8 b; } onesu;
  onesu.u[0] = onesu.u[1] = onesu.u[2] = onesu.u[3] = 0x3F803F80u;
  const bf16x8 onesb = onesu.b;

  floatx4 o[2][4];
  floatx4 lsum[2];
#pragma unroll
  for (int g = 0; g < 2; ++g) {
    lsum[g] = (floatx4)(0.f);
#pragma unroll
    for (int d = 0; d < 4; ++d) o[g][d] = (floatx4)(0.f);
  }

  const size_t kb = (size_t)bh * SEQ * HEAD_DIM;
  const size_t vb = (size_t)bh * HEAD_DIM * SEQ;

  // S^T fragments for one 32-key chunk: 8 MFMAs, depends only on Ks.
  auto sfrag = [&](int J2, floatx4 zz[2][2]) {
#pragma unroll
    for (int jj = 0; jj < 2; ++jj) {
      const int row = (J2*2 + jj)*16 + fr;  // key row in Ks
      bf16x8 k0 = *(const bf16x8*)&Ks[row*64 + ((fq ^ fx)*8)];
      bf16x8 k1 = *(const bf16x8*)&Ks[row*64 + (((fq+4) ^ fx)*8)];
#pragma unroll
      for (int g = 0; g < 2; ++g) {
        floatx4 a = (floatx4)(0.f);
        a = __builtin_amdgcn_mfma_f32_16x16x32_bf16(k0, aq[g][0], a, 0, 0, 0);
        a = __builtin_amdgcn_mfma_f32_16x16x32_bf16(k1, aq[g][1], a, 0, 0, 0);
        zz[g][jj] = a;                      // S^T: key=16(2J+jj)+fq*4+r, q=fr
      }
    }
  };

  for (int kc = 0; kc < SEQ; kc += 128) {
    __syncthreads();
#pragma unroll
    for (int i = 0; i < 4; ++i) {           // Ks: 1024 chunks, rows of 8
      const int chunk = i*256 + t;
      const int r = chunk >> 3, c = chunk & 7;
      async_cp16(&Ks[chunk*8], &Kb[kb + (size_t)(kc + r)*HEAD_DIM + ((c ^ (r&7))*8)]);
    }
#pragma unroll
    for (int i = 0; i < 4; ++i) {           // Vs: 2 halves x 512 chunks, rows of 8
      const int chunk = i*256 + t;
      const int h = chunk >> 9, rem = chunk & 511;
      const int r = rem >> 3, c = rem & 7;
      async_cp16(&Vs[0][0] + chunk*8,
                 &Vt[vb + (size_t)r*SEQ + kc + h*64 + ((c ^ (r&7))*8)]);
    }
    __syncthreads();

    floatx4 z[2][2];
    sfrag(0, z);
#pragma unroll
    for (int J = 0; J < 4; ++J) {           // 32-key chunks, pipelined
      floatx4 zn[2][2];
      if (J < 3) sfrag(J+1, zn);            // next chunk's S-MFMAs: in-flight
                                            // during this chunk's exp2 burst
      bf16x8 ap[2];
#pragma unroll
      for (int g = 0; g < 2; ++g) {
        float e0 = __builtin_amdgcn_exp2f(z[g][0][0]);
        float e1 = __builtin_amdgcn_exp2f(z[g][0][1]);
        float e2 = __builtin_amdgcn_exp2f(z[g][0][2]);
        float e3 = __builtin_amdgcn_exp2f(z[g][0][3]);
        float e4 = __builtin_amdgcn_exp2f(z[g][1][0]);
        float e5 = __builtin_amdgcn_exp2f(z[g][1][1]);
        float e6 = __builtin_amdgcn_exp2f(z[g][1][2]);
        float e7 = __builtin_amdgcn_exp2f(z[g][1][3]);
        union { unsigned int u[4]; bf16x8 b; } cv;
        cv.u[0] = pack_bf2_trunc(e0, e1);
        cv.u[1] = pack_bf2_trunc(e2, e3);
        cv.u[2] = pack_bf2_trunc(e4, e5);
        cv.u[3] = pack_bf2_trunc(e6, e7);
        ap[g] = cv.b;
      }
      // l += P * ones  (row-sum on the MFMA pipe; D rows = q like O)
#pragma unroll
      for (int g = 0; g < 2; ++g)
        lsum[g] = __builtin_amdgcn_mfma_f32_16x16x32_bf16(ap[g], onesb, lsum[g], 0, 0, 0);
      // PV: O[q][d] += P[q][key] V[key][d] over keys [32J, 32J+32)
      const unsigned short* vsh = &Vs[J >> 1][0];
      const int vc = ((4*(J & 1) + fq) ^ fx) * 8;
#pragma unroll
      for (int dt = 0; dt < 4; ++dt) {
        const bf16x8 vvb = *(const bf16x8*)&vsh[(dt*16 + fr)*64 + vc];
#pragma unroll
        for (int g = 0; g < 2; ++g)
          o[g][dt] = __builtin_amdgcn_mfma_f32_16x16x32_bf16(ap[g], vvb, o[g][dt], 0, 0, 0);
      }
      if (J < 3) {
#pragma unroll
        for (int g = 0; g < 2; ++g)
#pragma unroll
          for (int jj = 0; jj < 2; ++jj) z[g][jj] = zn[g][jj];
      }
    }
  }

  const int b = bh / NUM_HEADS, hh = bh - b*NUM_HEADS;
#pragma unroll
  for (int g = 0; g < 2; ++g)
#pragma unroll
    for (int r4 = 0; r4 < 4; ++r4) {
      const float li = 1.0f / lsum[g][r4];  // l[q=fq*4+r4] — same layout as O
      const size_t obase = ((size_t)b*SEQ + q0 + g*16 + fq*4 + r4)*EMB + hh*HEAD_DIM;
#pragma unroll
      for (int dt = 0; dt < 4; ++dt)
        Oo[obase + dt*16 + fr] = f2bf(o[g][dt][r4] * li);
    }
}

// ---------------- residual + LayerNorm: one wave per row ----------------
__global__ __launch_bounds__(256) void ln_kernel(
    const float* __restrict__ x, const unsigned short* __restrict__ att,
    const float* __restrict__ gamma, const float* __restrict__ beta,
    float* __restrict__ out) {
  const int row = blockIdx.x * 4 + (threadIdx.x >> 6);
  const int lane = threadIdx.x & 63;
  const size_t base = (size_t)row * EMB;
  float4 v[3];
  float s = 0.f, s2 = 0.f;
#pragma unroll
  for (int k = 0; k < 3; ++k) {
    const int c = lane*4 + k*256;
    const float4 xv = *(const float4*)&x[base + c];
    const ushort4 a4 = *(const ushort4*)&att[base + c];
    v[k].x = xv.x + bf2f(a4.x);
    v[k].y = xv.y + bf2f(a4.y);
    v[k].z = xv.z + bf2f(a4.z);
    v[k].w = xv.w + bf2f(a4.w);
    s  += (v[k].x + v[k].y) + (v[k].z + v[k].w);
    s2 += (v[k].x*v[k].x + v[k].y*v[k].y) + (v[k].z*v[k].z + v[k].w*v[k].w);
  }
#pragma unroll
  for (int off = 1; off < 64; off <<= 1) {
    s  += __shfl_xor(s,  off);
    s2 += __shfl_xor(s2, off);
  }
  const float mean = s * (1.0f / EMB);
  const float var  = s2 * (1.0f / EMB) - mean * mean;
  const float rstd = rsqrtf(var + 1e-5f);
#pragma unroll
  for (int k = 0; k < 3; ++k) {
    const int c = lane*4 + k*256;
    const float4 g4 = *(const float4*)&gamma[c];
    const float4 b4 = *(const float4*)&beta[c];
    float4 ov;
    ov.x = (v[k].x - mean) * rstd * g4.x + b4.x;
    ov.y = (v[k].y - mean) * rstd * g4.y + b4.y;
    ov.z = (v[k].z - mean) * rstd * g4.z + b4.z;
    ov.w = (v[k].w - mean) * rstd * g4.w + b4.w;
    *(float4*)&out[base + c] = ov;
  }
}

extern "C" void kernel_launch(void* const* d_in, const int* in_sizes, int n_in,
                              void* d_out, int out_size, void* d_ws, size_t ws_size,
                              hipStream_t stream) {
  const float* x      = (const float*)d_in[0];
  const float* w_qkv  = (const float*)d_in[1];
  const float* b_qkv  = (const float*)d_in[2];
  const float* gamma  = (const float*)d_in[3];
  const float* beta   = (const float*)d_in[4];
  float* out = (float*)d_out;

  unsigned short* xb = (unsigned short*)d_ws;                 // 8192*768 bf16
  unsigned short* wb = xb + (size_t)ROWS * EMB;               // 2304*768 bf16
  unsigned short* Qb = wb + (size_t)DQKV * EMB;               // [b,h,n,64] bf16 (scaled)
  unsigned short* Kb = Qb + (size_t)ROWS * EMB;               // [b,h,n,64] bf16
  unsigned short* Vt = Kb + (size_t)ROWS * EMB;               // [b,h,64,perm n] bf16
  unsigned short* att = Vt + (size_t)ROWS * EMB;              // [b,n,768] bf16

  cvt2_kernel<<<(N4X + N4W + 255)/256, 256, 0, stream>>>(x, w_qkv, xb, wb);
  qkv_gemm_kernel<<<dim3(ROWS/128, DQKV/128), 256, 0, stream>>>(xb, wb, b_qkv, Qb, Kb, Vt);
  attn_kernel<<<dim3(SEQ/128, BATCH*NUM_HEADS), 256, 0, stream>>>(Qb, Kb, Vt, att);
  ln_kernel<<<ROWS/4, 256, 0, stream>>>(x, att, gamma, beta, out);
}